// Round 2
// baseline (142.641 us; speedup 1.0000x reference)
//
#include <hip/hip_runtime.h>

// Problem constants (fixed by reference setup_inputs)
#define NUMB 32     // num
#define NTOP 32     // num_top
#define COBJ 4      // cobj
#define BAG  300    // bag_size
#define DD   256    // feature dim
#define HHID 256    // relation hidden
#define LL   128    // NTOP*COBJ
#define POOL 1200   // COBJ*BAG

// ---------------------------------------------------------------------------
// Kernel 1: gather + GEMM.
// Hout layout: [side(2)][n(32)][a(128)][h(256)]  (side-major rows, 8192x256)
// H0 = f0 @ W1a + b1 ; H1 = f1 @ W1b
// Tiles: 64x64, BK=16, 256 threads, 4x4 micro-tile per thread.
// ---------------------------------------------------------------------------
__global__ __launch_bounds__(256) void k_h01(
    const float* __restrict__ fea,
    const int*   __restrict__ ind0,
    const int*   __restrict__ ind1,
    const float* __restrict__ W1a,
    const float* __restrict__ W1b,
    const float* __restrict__ b1,
    float*       __restrict__ Hout)
{
    const int bm = blockIdx.x >> 2;   // row tile 0..127
    const int bn = blockIdx.x & 3;    // col tile 0..3
    const int t  = threadIdx.x;

    __shared__ float As[16][68];      // [k][m], pad to 68 to spread banks
    __shared__ float Bs[16][68];      // [k][n]

    const int side = (bm >= 64);      // block-uniform: 64 | 4096

    // A (gathered) load mapping: each thread loads one float4 of its row-chunk
    const int lr = t >> 2;            // local row 0..63
    const int kc = (t & 3) << 2;      // k offset within tile: 0,4,8,12
    const int grow = bm * 64 + lr;    // global row
    const int n_   = (grow >> 7) & 31;
    const int a_   = grow & 127;
    const int id   = (side ? ind1 : ind0)[n_ * LL + a_] + BAG * (a_ & 3);
    const float* arow = fea + (size_t)((n_ * 2 + side) * POOL + id) * DD;
    const float* Wm   = side ? W1b : W1a;

    const int tn = t & 15, tm = t >> 4;

    float c[4][4] = {{0.f,0.f,0.f,0.f},{0.f,0.f,0.f,0.f},
                     {0.f,0.f,0.f,0.f},{0.f,0.f,0.f,0.f}};

    for (int kk = 0; kk < DD; kk += 16) {
        float4 av = *(const float4*)(arow + kk + kc);
        float4 bv = *(const float4*)(Wm + (size_t)(kk + tm) * HHID + bn * 64 + tn * 4);
        __syncthreads();   // protect previous iteration's reads
        As[kc + 0][lr] = av.x;
        As[kc + 1][lr] = av.y;
        As[kc + 2][lr] = av.z;
        As[kc + 3][lr] = av.w;
        *(float4*)&Bs[tm][tn * 4] = bv;
        __syncthreads();
#pragma unroll
        for (int k = 0; k < 16; ++k) {
            float4 af = *(float4*)&As[k][tm * 4];
            float4 bf = *(float4*)&Bs[k][tn * 4];
            float ar[4] = {af.x, af.y, af.z, af.w};
            float br[4] = {bf.x, bf.y, bf.z, bf.w};
#pragma unroll
            for (int r = 0; r < 4; ++r)
#pragma unroll
                for (int s = 0; s < 4; ++s)
                    c[r][s] = fmaf(ar[r], br[s], c[r][s]);
        }
    }

    // epilogue: + b1 for side 0 only
    const int colb = bn * 64 + tn * 4;
    float4 bias;
    if (!side) bias = *(const float4*)(b1 + colb);
    else { bias.x = bias.y = bias.z = bias.w = 0.f; }
#pragma unroll
    for (int r = 0; r < 4; ++r) {
        const int row = bm * 64 + tm * 4 + r;
        float4 o;
        o.x = c[r][0] + bias.x;
        o.y = c[r][1] + bias.y;
        o.z = c[r][2] + bias.z;
        o.w = c[r][3] + bias.w;
        *(float4*)(Hout + (size_t)row * HHID + colb) = o;
    }
}

// ---------------------------------------------------------------------------
// Kernel 2: output init.
// out[0 .. 32767]           : scores, init to 16*b2 (patch of 4x4 b2 adds)
// out[32768 .. 98303]       : pairs as float: [n][p][2] with (p/32, p%32)
// ---------------------------------------------------------------------------
__global__ __launch_bounds__(256) void k_init(
    const float* __restrict__ b2, float* __restrict__ out)
{
    const int NS = NUMB * NTOP * NTOP;  // 32768
    int i = blockIdx.x * 256 + threadIdx.x;
    if (i < NS) {
        out[i] = 16.0f * b2[0];
    } else if (i < 3 * NS) {
        int j = i - NS;            // flat into [n][1024][2]
        int p = (j >> 1) & 1023;
        out[i] = (j & 1) ? (float)(p & 31) : (float)(p >> 5);
    }
}

// ---------------------------------------------------------------------------
// Kernel 3: pairwise relu-reduce with 4x4 patch fold.
// grid = ((n*2 + it)*2 + jt)*4 + hs  -> 512 blocks, 256 threads.
// Each block: n, a-rows [it*64, it*64+64), b-rows [jt*64, ...), h-chunk hs*64.
// Thread (il, jl) computes partial score for output (i=it*16+il, j=jt*16+jl),
// summing its 4x4 (a,b) patch over 64 h. atomicAdd merges the 4 h-splits.
// LDS layout XOR-swizzled: store unit f of row at position f ^ ((row>>2)&7).
// Read back with the SAME 3-bit mask: a-side rows are il*4+r so the mask is
// (il & 7)  [bug fixed: was f ^ il, wrong for il >= 8].
// ---------------------------------------------------------------------------
__global__ __launch_bounds__(256) void k_pair(
    const float* __restrict__ Hbuf,
    const float* __restrict__ W2,
    float*       __restrict__ out)
{
    int b = blockIdx.x;
    const int hs = b & 3;  b >>= 2;
    const int jt = b & 1;  b >>= 1;
    const int it = b & 1;  b >>= 1;
    const int n  = b;

    __shared__ float s0[64 * 64];
    __shared__ float s1[64 * 64];
    __shared__ float w2s[64];

    const int t = threadIdx.x;
    const float* H0 = Hbuf + ((size_t)(n * LL) + it * 64) * HHID + hs * 64;
    const float* H1 = Hbuf + ((size_t)(NUMB * LL) + n * LL + jt * 64) * HHID + hs * 64;

#pragma unroll
    for (int rep = 0; rep < 4; ++rep) {
        int idx = rep * 256 + t;
        int row = idx >> 4;          // 0..63
        int f   = idx & 15;          // 16B unit within the 64-float row
        int fs  = f ^ ((row >> 2) & 7);
        float4 v0 = *(const float4*)(H0 + (size_t)row * HHID + f * 4);
        float4 v1 = *(const float4*)(H1 + (size_t)row * HHID + f * 4);
        *(float4*)&s0[row * 64 + fs * 4] = v0;
        *(float4*)&s1[row * 64 + fs * 4] = v1;
    }
    if (t < 16) *(float4*)&w2s[t * 4] = *(const float4*)(W2 + hs * 64 + t * 4);
    __syncthreads();

    const int jl = t & 15, il = t >> 4;
    float acc[4][4] = {{0.f,0.f,0.f,0.f},{0.f,0.f,0.f,0.f},
                       {0.f,0.f,0.f,0.f},{0.f,0.f,0.f,0.f}};

#pragma unroll
    for (int f = 0; f < 16; ++f) {
        float4 w = *(float4*)&w2s[f * 4];
        float4 a[4], bb[4];
#pragma unroll
        for (int r = 0; r < 4; ++r)
            a[r] = *(float4*)&s0[(il * 4 + r) * 64 + (f ^ (il & 7)) * 4];
#pragma unroll
        for (int s = 0; s < 4; ++s)
            bb[s] = *(float4*)&s1[(jl * 4 + s) * 64 + (f ^ (jl & 7)) * 4];
#pragma unroll
        for (int r = 0; r < 4; ++r)
#pragma unroll
            for (int s = 0; s < 4; ++s) {
                acc[r][s] = fmaf(fmaxf(a[r].x + bb[s].x, 0.f), w.x, acc[r][s]);
                acc[r][s] = fmaf(fmaxf(a[r].y + bb[s].y, 0.f), w.y, acc[r][s]);
                acc[r][s] = fmaf(fmaxf(a[r].z + bb[s].z, 0.f), w.z, acc[r][s]);
                acc[r][s] = fmaf(fmaxf(a[r].w + bb[s].w, 0.f), w.w, acc[r][s]);
            }
    }

    float sum = 0.f;
#pragma unroll
    for (int r = 0; r < 4; ++r)
#pragma unroll
        for (int s = 0; s < 4; ++s) sum += acc[r][s];

    atomicAdd(out + n * 1024 + (it * 16 + il) * 32 + jt * 16 + jl, sum);
}

// ---------------------------------------------------------------------------
extern "C" void kernel_launch(void* const* d_in, const int* in_sizes, int n_in,
                              void* d_out, int out_size, void* d_ws, size_t ws_size,
                              hipStream_t stream)
{
    const float* fea  = (const float*)d_in[0];
    const int*   ind0 = (const int*)  d_in[1];
    const int*   ind1 = (const int*)  d_in[2];
    // d_in[3] = k (scalar 8, compile-time constant here)
    const float* W1a  = (const float*)d_in[4];
    const float* W1b  = (const float*)d_in[5];
    const float* b1   = (const float*)d_in[6];
    const float* W2   = (const float*)d_in[7];
    const float* b2   = (const float*)d_in[8];
    float* out  = (float*)d_out;
    float* Hbuf = (float*)d_ws;    // needs 8192*256*4 = 8 MiB

    hipLaunchKernelGGL(k_h01, dim3(512), dim3(256), 0, stream,
                       fea, ind0, ind1, W1a, W1b, b1, Hbuf);
    hipLaunchKernelGGL(k_init, dim3(384), dim3(256), 0, stream, b2, out);
    hipLaunchKernelGGL(k_pair, dim3(512), dim3(256), 0, stream,
                       Hbuf, W2, out);
}

// Round 4
// 131.240 us; speedup vs baseline: 1.0869x; 1.0869x over previous
//
#include <hip/hip_runtime.h>

// Problem constants (fixed by reference setup_inputs)
#define NUMB 32     // num
#define LL   128    // num_top*cobj
#define POOL 1200   // cobj*bag
#define BAG  300
#define DD   256    // feature dim
#define HH   256    // relation hidden
#define NS   (NUMB*32*32)   // 32768 scores

using bf16x8 = __bf16    __attribute__((ext_vector_type(8)));
using f32x4  = float     __attribute__((ext_vector_type(4)));
using fp16x2 = __fp16    __attribute__((ext_vector_type(2)));  // cvt_pkrtz result
using h16x2  = _Float16  __attribute__((ext_vector_type(2)));  // fdot2 operand
using h16x8  = _Float16  __attribute__((ext_vector_type(8)));

typedef const __attribute__((address_space(1))) unsigned int* gas_t;
typedef       __attribute__((address_space(3))) unsigned int* las_t;

static __device__ __forceinline__ unsigned short f2bf(float x) {
    unsigned u = __float_as_uint(x);
    return (unsigned short)((u + 0x7FFFu + ((u >> 16) & 1u)) >> 16);  // RNE
}

static __device__ __forceinline__ float pkh(float a, float b) {
    fp16x2 p = __builtin_amdgcn_cvt_pkrtz(a, b);
    return __builtin_bit_cast(float, p);
}

// ---------------------------------------------------------------------------
// K0: prep.
//  blocks 0..31  : W transpose+convert -> WtP bf16, pre-swizzled:
//                  WtP[((side*4+ht)*64+nn)*32 + (U ^ (nn&7))] = Wt[h][k-unit U]
//                  (unit = 8 bf16 = 16B; h = ht*64+nn; Wt[h][k] = W[k][h])
//  blocks 32..415: out init: scores = 16*b2, pairs = (p/32, p%32) as float
// ---------------------------------------------------------------------------
__global__ __launch_bounds__(256) void k_prep(
    const float* __restrict__ W1a, const float* __restrict__ W1b,
    const float* __restrict__ b2,
    unsigned short* __restrict__ WtP, float* __restrict__ out)
{
    const int blk = blockIdx.x, t = threadIdx.x;
    if (blk < 32) {
        const int side = blk >> 4, kc = blk & 15;   // k-chunk of 16
        const float* W = side ? W1b : W1a;          // [k][h] row-major
        __shared__ float T[16][257];
        const int row = t >> 4, c = t & 15;
#pragma unroll
        for (int i = 0; i < 4; ++i) {
            int col4 = c + i * 16;
            float4 v = *(const float4*)(W + (size_t)(kc * 16 + row) * HH + col4 * 4);
            T[row][col4 * 4 + 0] = v.x; T[row][col4 * 4 + 1] = v.y;
            T[row][col4 * 4 + 2] = v.z; T[row][col4 * 4 + 3] = v.w;
        }
        __syncthreads();
        const int n = t, ht = n >> 6, nn = n & 63;
#pragma unroll
        for (int j = 0; j < 2; ++j) {
            unsigned short tmp[8] __attribute__((aligned(16)));
#pragma unroll
            for (int e = 0; e < 8; ++e) tmp[e] = f2bf(T[j * 8 + e][n]);
            int U = kc * 2 + j;
            int pos = U ^ (nn & 7);
            size_t unit = ((size_t)((side * 4 + ht) * 64 + nn)) * 32 + pos;
            *(float4*)(WtP + unit * 8) = *(float4*)tmp;
        }
    } else {
        int i = (blk - 32) * 256 + t;
        if (i < NS) {
            out[i] = 16.0f * b2[0];
        } else if (i < 3 * NS) {
            int j = i - NS;
            int p = (j >> 1) & 1023;
            out[i] = (j & 1) ? (float)(p & 31) : (float)(p >> 5);
        }
    }
}

// ---------------------------------------------------------------------------
// K1: gather + bf16 MFMA GEMM, computing H^T = Wt * F^T per tile.
//  Tile: M=64 h-rows (A = WtP quarter, via global_load_lds, pre-swizzled),
//        N=64 gathered feature rows (B, fp32->bf16 convert, swizzled ds_write),
//        K=256 fully staged. LDS = 32KB + 32KB. 256 thr, 1 barrier.
//  grid = rt(128) * ht(4) = 512.  Wave w handles h-subtile w x 4 row-bands.
//  D layout (16x16x32): col = lane&15 = feature-row, row = quad*4+reg = h
//  -> 4 consecutive h per lane -> pack fp16 -> one 8B store into Hh[row][h].
// ---------------------------------------------------------------------------
__global__ __launch_bounds__(256) void k_gemm(
    const float* __restrict__ fea,
    const int*   __restrict__ ind0,
    const int*   __restrict__ ind1,
    const float* __restrict__ b1,
    const unsigned short* __restrict__ WtP,
    unsigned short* __restrict__ Hh)
{
    __shared__ unsigned short As[64 * 256] __attribute__((aligned(16))); // 32KB bf16
    __shared__ unsigned short Bs[64 * 256] __attribute__((aligned(16))); // 32KB bf16

    int b = blockIdx.x;
    const int ht = b & 3, rt = b >> 2;
    const int side = rt >> 6;
    const int R0 = rt * 64;
    const int t = threadIdx.x, w = t >> 6, lane = t & 63;

    // --- A staging: async global->LDS, layout already swizzled in WtP ---
    const unsigned short* Wbase = WtP + ((size_t)(side * 4 + ht)) * 64 * 256;
#pragma unroll
    for (int i = 0; i < 8; ++i) {
        int chunk = w * 8 + i;               // 32 chunks of 1KB
        __builtin_amdgcn_global_load_lds(
            (gas_t)(const void*)(Wbase + chunk * 512 + lane * 8),
            (las_t)(void*)(As + chunk * 512),
            16, 0, 0);
    }

    // --- B staging: gather fp32 row, convert bf16, swizzled ds_write ---
    {
        const int lr = t >> 2;               // local row 0..63
        const int g = R0 + lr;
        const int rs = g & 4095, n_ = rs >> 7, a_ = rs & 127;
        const int id = (side ? ind1 : ind0)[n_ * LL + a_] + BAG * (a_ & 3);
        const float* arow = fea + (size_t)((n_ * 2 + side) * POOL + id) * DD;
        const int sw = lr & 7;
#pragma unroll
        for (int j0 = 0; j0 < 16; ++j0) {
            int jj = j0 * 4 + (t & 3);       // float4 index 0..63 in row
            float4 v = *(const float4*)(arow + jj * 4);
            unsigned short tmp[4] __attribute__((aligned(8)));
            tmp[0] = f2bf(v.x); tmp[1] = f2bf(v.y);
            tmp[2] = f2bf(v.z); tmp[3] = f2bf(v.w);
            int u = jj >> 1, pos = u ^ sw;
            *(double*)&Bs[lr * 256 + pos * 8 + (jj & 1) * 4] = *(double*)tmp;
        }
    }
    __syncthreads();   // drains global_load_lds (vmcnt) + ds_writes

    // --- K loop: 8 steps of K=32, pure LDS->MFMA ---
    const int l15 = lane & 15, q = lane >> 4;
    f32x4 acc[4] = {};                       // 4 row-bands
#pragma unroll
    for (int kk = 0; kk < 8; ++kk) {
        const int u = kk * 4 + q;
        const int hr = w * 16 + l15;         // h row in [0,64)
        bf16x8 af = *(const bf16x8*)&As[hr * 256 + (u ^ (hr & 7)) * 8];
        bf16x8 bf[4];
#pragma unroll
        for (int rb = 0; rb < 4; ++rb) {
            int r = rb * 16 + l15;
            bf[rb] = *(const bf16x8*)&Bs[r * 256 + (u ^ (r & 7)) * 8];
        }
#pragma unroll
        for (int rb = 0; rb < 4; ++rb)
            acc[rb] = __builtin_amdgcn_mfma_f32_16x16x32_bf16(af, bf[rb], acc[rb], 0, 0, 0);
    }

    // --- epilogue: +b1 (side 0), fp32 -> fp16, 8B stores into Hh[row][h] ---
    const int hbase = ht * 64 + w * 16 + q * 4;
    float4 bias = make_float4(0.f, 0.f, 0.f, 0.f);
    if (side == 0) bias = *(const float4*)(b1 + hbase);
#pragma unroll
    for (int rb = 0; rb < 4; ++rb) {
        int frow = R0 + rb * 16 + l15;
        float2 pk;
        pk.x = pkh(acc[rb][0] + bias.x, acc[rb][1] + bias.y);
        pk.y = pkh(acc[rb][2] + bias.z, acc[rb][3] + bias.w);
        *(float2*)&Hh[(size_t)frow * HH + hbase] = pk;
    }
}

// ---------------------------------------------------------------------------
// K2: pairwise relu-reduce, fp16 packed + v_dot2_f32_f16 (fp32 accumulate).
//  grid = ((n*2+it)*2+jt)*4+hs -> 512 blocks; block covers 64 a-rows x
//  64 b-rows x 64 h. Thread (il,jl): 4x4 patch -> one output, atomicAdd over
//  the 4 h-splits. LDS tiles fp16, 16B-unit XOR swizzle by ((row>>2)&7),
//  staged via global_load_lds with the swizzle folded into the global address.
// ---------------------------------------------------------------------------
__global__ __launch_bounds__(256) void k_pair(
    const unsigned short* __restrict__ Hh,
    const float* __restrict__ W2,
    float*       __restrict__ out)
{
    __shared__ unsigned short s0[64 * 64] __attribute__((aligned(16))); // 8KB fp16
    __shared__ unsigned short s1[64 * 64] __attribute__((aligned(16))); // 8KB fp16
    __shared__ unsigned short w2s[64]     __attribute__((aligned(16)));

    int b = blockIdx.x;
    const int hs = b & 3;  b >>= 2;
    const int jt = b & 1;  b >>= 1;
    const int it = b & 1;  b >>= 1;
    const int n  = b;
    const int t = threadIdx.x, w = t >> 6, lane = t & 63;

    const size_t base0 = ((size_t)(n * LL) + it * 64) * HH + hs * 64;
    const size_t base1 = ((size_t)(NUMB * LL + n * LL) + jt * 64) * HH + hs * 64;

    // async staging: LDS slot (row, posslot) holds h-unit f = posslot ^ ((row>>2)&7)
    {
        const int lrow = lane >> 3, posslot = lane & 7;
#pragma unroll
        for (int i = 0; i < 2; ++i) {
            int chunk = w * 2 + i;               // 8 chunks of 8 rows
            int row = chunk * 8 + lrow;
            int f = posslot ^ ((row >> 2) & 7);
            __builtin_amdgcn_global_load_lds(
                (gas_t)(const void*)(Hh + base0 + (size_t)row * HH + f * 8),
                (las_t)(void*)(s0 + chunk * 512), 16, 0, 0);
            __builtin_amdgcn_global_load_lds(
                (gas_t)(const void*)(Hh + base1 + (size_t)row * HH + f * 8),
                (las_t)(void*)(s1 + chunk * 512), 16, 0, 0);
        }
    }
    if (t < 16) {
        float4 v = *(const float4*)(W2 + hs * 64 + t * 4);
        float2 pk;
        pk.x = pkh(v.x, v.y);
        pk.y = pkh(v.z, v.w);
        *(float2*)&w2s[t * 4] = pk;
    }
    __syncthreads();

    const int jl = t & 15, il = t >> 4;
    float acc[4][4] = {{0.f,0.f,0.f,0.f},{0.f,0.f,0.f,0.f},
                       {0.f,0.f,0.f,0.f},{0.f,0.f,0.f,0.f}};

#pragma unroll
    for (int f = 0; f < 8; ++f) {
        h16x8 wv = *(const h16x8*)&w2s[f * 8];          // broadcast, free
        const h16x2* wp = (const h16x2*)&wv;
        h16x8 av[4], bv[4];
#pragma unroll
        for (int r = 0; r < 4; ++r)
            av[r] = *(const h16x8*)&s0[(il * 4 + r) * 64 + (f ^ (il & 7)) * 8];
#pragma unroll
        for (int s = 0; s < 4; ++s)
            bv[s] = *(const h16x8*)&s1[(jl * 4 + s) * 64 + (f ^ (jl & 7)) * 8];
        const h16x8 zero = {0, 0, 0, 0, 0, 0, 0, 0};
#pragma unroll
        for (int r = 0; r < 4; ++r)
#pragma unroll
            for (int s = 0; s < 4; ++s) {
                h16x8 sum = av[r] + bv[s];              // v_pk_add_f16 x4
                sum = __builtin_elementwise_max(sum, zero); // v_pk_max_f16 x4
                const h16x2* sp = (const h16x2*)&sum;
#pragma unroll
                for (int u = 0; u < 4; ++u)
                    acc[r][s] = __builtin_amdgcn_fdot2(sp[u], wp[u], acc[r][s], false);
            }
    }

    float total = 0.f;
#pragma unroll
    for (int r = 0; r < 4; ++r)
#pragma unroll
        for (int s = 0; s < 4; ++s) total += acc[r][s];

    atomicAdd(out + n * 1024 + (it * 16 + il) * 32 + jt * 16 + jl, total);
}

// ---------------------------------------------------------------------------
extern "C" void kernel_launch(void* const* d_in, const int* in_sizes, int n_in,
                              void* d_out, int out_size, void* d_ws, size_t ws_size,
                              hipStream_t stream)
{
    const float* fea  = (const float*)d_in[0];
    const int*   ind0 = (const int*)  d_in[1];
    const int*   ind1 = (const int*)  d_in[2];
    // d_in[3] = k (scalar 8, compile-time constant here)
    const float* W1a  = (const float*)d_in[4];
    const float* W1b  = (const float*)d_in[5];
    const float* b1   = (const float*)d_in[6];
    const float* W2   = (const float*)d_in[7];
    const float* b2   = (const float*)d_in[8];
    float* out = (float*)d_out;

    unsigned short* WtP = (unsigned short*)d_ws;                 // 256KB bf16
    unsigned short* Hh  = (unsigned short*)((char*)d_ws + 512 * 1024); // 4MB fp16

    hipLaunchKernelGGL(k_prep, dim3(416), dim3(256), 0, stream,
                       W1a, W1b, b2, WtP, out);
    hipLaunchKernelGGL(k_gemm, dim3(512), dim3(256), 0, stream,
                       fea, ind0, ind1, b1, WtP, Hh);
    hipLaunchKernelGGL(k_pair, dim3(512), dim3(256), 0, stream,
                       Hh, W2, out);
}

// Round 5
// 130.861 us; speedup vs baseline: 1.0900x; 1.0029x over previous
//
#include <hip/hip_runtime.h>

// Problem constants (fixed by reference setup_inputs)
#define NUMB 32     // num
#define LL   128    // num_top*cobj
#define POOL 1200   // cobj*bag
#define BAG  300
#define DD   256    // feature dim
#define HH   256    // relation hidden
#define NS   (NUMB*32*32)   // 32768 scores

using bf16x8 = __bf16    __attribute__((ext_vector_type(8)));
using f32x4  = float     __attribute__((ext_vector_type(4)));
using fp16x2 = __fp16    __attribute__((ext_vector_type(2)));  // cvt_pkrtz result
using h16x2  = _Float16  __attribute__((ext_vector_type(2)));  // fdot2 operand
using h16x8  = _Float16  __attribute__((ext_vector_type(8)));

typedef const __attribute__((address_space(1))) unsigned int* gas_t;
typedef       __attribute__((address_space(3))) unsigned int* las_t;

static __device__ __forceinline__ unsigned short f2bf(float x) {
    unsigned u = __float_as_uint(x);
    return (unsigned short)((u + 0x7FFFu + ((u >> 16) & 1u)) >> 16);  // RNE
}

static __device__ __forceinline__ float pkh(float a, float b) {
    fp16x2 p = __builtin_amdgcn_cvt_pkrtz(a, b);
    return __builtin_bit_cast(float, p);
}

// ---------------------------------------------------------------------------
// K0: prep.
//  blocks 0..31 : W transpose+convert -> WtP bf16, pre-swizzled:
//                 WtP[((side*4+ht)*64+nn)*32 + (U ^ (nn&7))] = Wt[h][k-unit U]
//                 (unit = 8 bf16 = 16B; h = ht*64+nn; Wt[h][k] = W[k][h])
//  blocks 32..95: pairs init (float4): pairs[n][p][2] = (p>>5, p&31) as float
//                 (scores region is now written directly by k_pair — no init)
// ---------------------------------------------------------------------------
__global__ __launch_bounds__(256) void k_prep(
    const float* __restrict__ W1a, const float* __restrict__ W1b,
    unsigned short* __restrict__ WtP, float* __restrict__ out)
{
    const int blk = blockIdx.x, t = threadIdx.x;
    if (blk < 32) {
        const int side = blk >> 4, kc = blk & 15;   // k-chunk of 16
        const float* W = side ? W1b : W1a;          // [k][h] row-major
        __shared__ float T[16][257];
        const int row = t >> 4, c = t & 15;
#pragma unroll
        for (int i = 0; i < 4; ++i) {
            int col4 = c + i * 16;
            float4 v = *(const float4*)(W + (size_t)(kc * 16 + row) * HH + col4 * 4);
            T[row][col4 * 4 + 0] = v.x; T[row][col4 * 4 + 1] = v.y;
            T[row][col4 * 4 + 2] = v.z; T[row][col4 * 4 + 3] = v.w;
        }
        __syncthreads();
        const int n = t, ht = n >> 6, nn = n & 63;
#pragma unroll
        for (int j = 0; j < 2; ++j) {
            unsigned short tmp[8] __attribute__((aligned(16)));
#pragma unroll
            for (int e = 0; e < 8; ++e) tmp[e] = f2bf(T[j * 8 + e][n]);
            int U = kc * 2 + j;
            int pos = U ^ (nn & 7);
            size_t unit = ((size_t)((side * 4 + ht) * 64 + nn)) * 32 + pos;
            *(float4*)(WtP + unit * 8) = *(float4*)tmp;
        }
    } else {
        // pairs region: 65536 floats = 16384 float4, pattern repeats per n
        int G = (blk - 32) * 256 + t;               // 0..16383
        int local = G & 511;                        // float4 within one n
        float i = (float)(local >> 4);
        float c0 = (float)((2 * local) & 31);
        ((float4*)(out + NS))[G] = make_float4(i, c0, i, c0 + 1.0f);
    }
}

// ---------------------------------------------------------------------------
// K1: gather + bf16 MFMA GEMM, computing H^T = Wt * F^T per tile.
//  Tile: M=64 h-rows (A = WtP quarter, via global_load_lds, pre-swizzled),
//        N=64 gathered feature rows (B, fp32->bf16 convert, swizzled ds_write),
//        K=256 fully staged. LDS = 32KB + 32KB. 256 thr, 1 barrier.
//  grid = rt(128) * ht(4) = 512.  Wave w handles h-subtile w x 4 row-bands.
//  D layout (16x16x32): col = lane&15 = feature-row, row = quad*4+reg = h
//  -> 4 consecutive h per lane -> pack fp16 -> one 8B store into Hh[row][h].
// ---------------------------------------------------------------------------
__global__ __launch_bounds__(256) void k_gemm(
    const float* __restrict__ fea,
    const int*   __restrict__ ind0,
    const int*   __restrict__ ind1,
    const float* __restrict__ b1,
    const unsigned short* __restrict__ WtP,
    unsigned short* __restrict__ Hh)
{
    __shared__ unsigned short As[64 * 256] __attribute__((aligned(16))); // 32KB bf16
    __shared__ unsigned short Bs[64 * 256] __attribute__((aligned(16))); // 32KB bf16

    int b = blockIdx.x;
    const int ht = b & 3, rt = b >> 2;
    const int side = rt >> 6;
    const int R0 = rt * 64;
    const int t = threadIdx.x, w = t >> 6, lane = t & 63;

    // --- A staging: async global->LDS, layout already swizzled in WtP ---
    const unsigned short* Wbase = WtP + ((size_t)(side * 4 + ht)) * 64 * 256;
#pragma unroll
    for (int i = 0; i < 8; ++i) {
        int chunk = w * 8 + i;               // 32 chunks of 1KB
        __builtin_amdgcn_global_load_lds(
            (gas_t)(const void*)(Wbase + chunk * 512 + lane * 8),
            (las_t)(void*)(As + chunk * 512),
            16, 0, 0);
    }

    // --- B staging: gather fp32 row, convert bf16, swizzled ds_write ---
    {
        const int lr = t >> 2;               // local row 0..63
        const int g = R0 + lr;
        const int rs = g & 4095, n_ = rs >> 7, a_ = rs & 127;
        const int id = (side ? ind1 : ind0)[n_ * LL + a_] + BAG * (a_ & 3);
        const float* arow = fea + (size_t)((n_ * 2 + side) * POOL + id) * DD;
        const int sw = lr & 7;
#pragma unroll
        for (int j0 = 0; j0 < 16; ++j0) {
            int jj = j0 * 4 + (t & 3);       // float4 index 0..63 in row
            float4 v = *(const float4*)(arow + jj * 4);
            unsigned short tmp[4] __attribute__((aligned(8)));
            tmp[0] = f2bf(v.x); tmp[1] = f2bf(v.y);
            tmp[2] = f2bf(v.z); tmp[3] = f2bf(v.w);
            int u = jj >> 1, pos = u ^ sw;
            *(double*)&Bs[lr * 256 + pos * 8 + (jj & 1) * 4] = *(double*)tmp;
        }
    }
    __syncthreads();   // drains global_load_lds (vmcnt) + ds_writes

    // --- K loop: 8 steps of K=32, pure LDS->MFMA ---
    const int l15 = lane & 15, q = lane >> 4;
    f32x4 acc[4] = {};                       // 4 row-bands
#pragma unroll
    for (int kk = 0; kk < 8; ++kk) {
        const int u = kk * 4 + q;
        const int hr = w * 16 + l15;         // h row in [0,64)
        bf16x8 af = *(const bf16x8*)&As[hr * 256 + (u ^ (hr & 7)) * 8];
        bf16x8 bf[4];
#pragma unroll
        for (int rb = 0; rb < 4; ++rb) {
            int r = rb * 16 + l15;
            bf[rb] = *(const bf16x8*)&Bs[r * 256 + (u ^ (r & 7)) * 8];
        }
#pragma unroll
        for (int rb = 0; rb < 4; ++rb)
            acc[rb] = __builtin_amdgcn_mfma_f32_16x16x32_bf16(af, bf[rb], acc[rb], 0, 0, 0);
    }

    // --- epilogue: +b1 (side 0), fp32 -> fp16, 8B stores into Hh[row][h] ---
    const int hbase = ht * 64 + w * 16 + q * 4;
    float4 bias = make_float4(0.f, 0.f, 0.f, 0.f);
    if (side == 0) bias = *(const float4*)(b1 + hbase);
#pragma unroll
    for (int rb = 0; rb < 4; ++rb) {
        int frow = R0 + rb * 16 + l15;
        float2 pk;
        pk.x = pkh(acc[rb][0] + bias.x, acc[rb][1] + bias.y);
        pk.y = pkh(acc[rb][2] + bias.z, acc[rb][3] + bias.w);
        *(float2*)&Hh[(size_t)frow * HH + hbase] = pk;
    }
}

// ---------------------------------------------------------------------------
// K2: pairwise relu-reduce, fp16 packed + v_dot2_f32_f16 (fp32 accumulate).
//  grid = n(32) x it(4) x jt(4) = 512 blocks; block covers 32 a-rows x
//  32 b-rows x ALL 256 h. Wave w = h-chunk w*64; thread (hq=w, il, jl) does a
//  4x4 (a,b) patch over its 64 h; cross-hq merge via LDS reduction; final
//  single store includes 16*b2 (no atomics, no score-init pass).
//  LDS tiles fp16 [32 rows x 256 h], 16B-unit swizzle pos = u ^ ((row>>2)&7)
//  folded into the global_load_lds source address; read patterns (rows
//  il*4+r, stride-4) land on 8 distinct 16B-columns -> conflict-free.
// ---------------------------------------------------------------------------
__global__ __launch_bounds__(256) void k_pair(
    const unsigned short* __restrict__ Hh,
    const float* __restrict__ W2,
    const float* __restrict__ b2,
    float*       __restrict__ out)
{
    __shared__ unsigned short s0[32 * 256] __attribute__((aligned(16))); // 16KB fp16
    __shared__ unsigned short s1[32 * 256] __attribute__((aligned(16))); // 16KB fp16
    __shared__ unsigned short w2s[256]     __attribute__((aligned(16)));
    __shared__ float sred[256];

    int b = blockIdx.x;
    const int jt = b & 3;  b >>= 2;
    const int it = b & 3;  b >>= 2;
    const int n  = b;
    const int t = threadIdx.x, w = t >> 6, lane = t & 63;

    const size_t base0 = ((size_t)(n * LL) + it * 32) * HH;
    const size_t base1 = ((size_t)(NUMB * LL + n * LL) + jt * 32) * HH;

    // async staging: wave w stages rows w*8..w*8+7 of both tiles.
    // Each issue covers 2 rows (64 lanes x 16B = 1KB); LDS slot (row,pos)
    // receives global h-unit f = pos ^ ((row>>2)&7).
    {
        const int pos = lane & 31, rhalf = lane >> 5;
#pragma unroll
        for (int i = 0; i < 4; ++i) {
            int rowbase = w * 8 + i * 2;
            int row = rowbase + rhalf;
            int f = pos ^ ((row >> 2) & 7);
            __builtin_amdgcn_global_load_lds(
                (gas_t)(const void*)(Hh + base0 + (size_t)row * HH + f * 8),
                (las_t)(void*)(s0 + rowbase * 256), 16, 0, 0);
            __builtin_amdgcn_global_load_lds(
                (gas_t)(const void*)(Hh + base1 + (size_t)row * HH + f * 8),
                (las_t)(void*)(s1 + rowbase * 256), 16, 0, 0);
        }
    }
    if (t < 64) {
        float4 v = *(const float4*)(W2 + t * 4);
        float2 pk;
        pk.x = pkh(v.x, v.y);
        pk.y = pkh(v.z, v.w);
        *(float2*)&w2s[t * 4] = pk;
    }
    __syncthreads();

    const int il = (t >> 3) & 7, jl = t & 7;
    float acc[4][4] = {{0.f,0.f,0.f,0.f},{0.f,0.f,0.f,0.f},
                       {0.f,0.f,0.f,0.f},{0.f,0.f,0.f,0.f}};

#pragma unroll
    for (int f = 0; f < 8; ++f) {
        h16x8 wv = *(const h16x8*)&w2s[(w * 8 + f) * 8];   // wave-uniform
        const h16x2* wp = (const h16x2*)&wv;
        h16x8 av[4], bv[4];
#pragma unroll
        for (int r = 0; r < 4; ++r)
            av[r] = *(const h16x8*)&s0[(il * 4 + r) * 256 + (w * 8 + (f ^ il)) * 8];
#pragma unroll
        for (int s = 0; s < 4; ++s)
            bv[s] = *(const h16x8*)&s1[(jl * 4 + s) * 256 + (w * 8 + (f ^ jl)) * 8];
        const h16x8 zero = {0, 0, 0, 0, 0, 0, 0, 0};
#pragma unroll
        for (int r = 0; r < 4; ++r)
#pragma unroll
            for (int s = 0; s < 4; ++s) {
                h16x8 sum = av[r] + bv[s];                  // v_pk_add_f16 x4
                sum = __builtin_elementwise_max(sum, zero); // v_pk_max_f16 x4
                const h16x2* sp = (const h16x2*)&sum;
#pragma unroll
                for (int u = 0; u < 4; ++u)
                    acc[r][s] = __builtin_amdgcn_fdot2(sp[u], wp[u], acc[r][s], false);
            }
    }

    float total = 0.f;
#pragma unroll
    for (int r = 0; r < 4; ++r)
#pragma unroll
        for (int s = 0; s < 4; ++s) total += acc[r][s];

    sred[t] = total;
    __syncthreads();

    if (t < 64) {
        float sum = sred[t] + sred[t + 64] + sred[t + 128] + sred[t + 192]
                  + 16.0f * b2[0];
        int i = it * 8 + (t >> 3);
        int j = jt * 8 + (t & 7);
        out[n * 1024 + i * 32 + j] = sum;
    }
}

// ---------------------------------------------------------------------------
extern "C" void kernel_launch(void* const* d_in, const int* in_sizes, int n_in,
                              void* d_out, int out_size, void* d_ws, size_t ws_size,
                              hipStream_t stream)
{
    const float* fea  = (const float*)d_in[0];
    const int*   ind0 = (const int*)  d_in[1];
    const int*   ind1 = (const int*)  d_in[2];
    // d_in[3] = k (scalar 8, compile-time constant here)
    const float* W1a  = (const float*)d_in[4];
    const float* W1b  = (const float*)d_in[5];
    const float* b1   = (const float*)d_in[6];
    const float* W2   = (const float*)d_in[7];
    const float* b2   = (const float*)d_in[8];
    float* out = (float*)d_out;

    unsigned short* WtP = (unsigned short*)d_ws;                 // 256KB bf16
    unsigned short* Hh  = (unsigned short*)((char*)d_ws + 512 * 1024); // 4MB fp16

    hipLaunchKernelGGL(k_prep, dim3(96), dim3(256), 0, stream,
                       W1a, W1b, WtP, out);
    hipLaunchKernelGGL(k_gemm, dim3(512), dim3(256), 0, stream,
                       fea, ind0, ind1, b1, WtP, Hh);
    hipLaunchKernelGGL(k_pair, dim3(512), dim3(256), 0, stream,
                       Hh, W2, b2, out);
}